// Round 11
// baseline (446.999 us; speedup 1.0000x reference)
//
#include <hip/hip_runtime.h>

#define L_LM 2000
#define F_DIM 64
#define B_SZ 2048
#define CL 16      // landmarks per delta block
#define CB 128     // batch rows per delta block

typedef float f32x4 __attribute__((ext_vector_type(4)));

// ---------------- Kernel 1: BMU (argmin of squared distance) ----------------
__global__ __launch_bounds__(256) void som_bmu_kernel(
    const float* __restrict__ x, const float* __restrict__ lm,
    int* __restrict__ min_idx)
{
    constexpr int ROWS = 8;
    const int b0 = blockIdx.x * ROWS;
    const int tid = threadIdx.x;

    __shared__ float xs[ROWS][F_DIM];
    for (int i = tid; i < ROWS * F_DIM; i += 256) {
        xs[i / F_DIM][i % F_DIM] = x[(size_t)(b0 + i / F_DIM) * F_DIM + (i % F_DIM)];
    }
    __syncthreads();

    float best[ROWS];
    int   bidx[ROWS];
#pragma unroll
    for (int r = 0; r < ROWS; ++r) { best[r] = 3.4e38f; bidx[r] = 0; }

    for (int l = tid; l < L_LM; l += 256) {
        const float4* lp = reinterpret_cast<const float4*>(lm + (size_t)l * F_DIM);
        float dot[ROWS];
        float l2 = 0.f;
#pragma unroll
        for (int r = 0; r < ROWS; ++r) dot[r] = 0.f;
#pragma unroll
        for (int k = 0; k < F_DIM / 4; ++k) {
            float4 v = lp[k];
            l2 += v.x * v.x + v.y * v.y + v.z * v.z + v.w * v.w;
#pragma unroll
            for (int r = 0; r < ROWS; ++r) {
                dot[r] += v.x * xs[r][4 * k + 0] + v.y * xs[r][4 * k + 1]
                        + v.z * xs[r][4 * k + 2] + v.w * xs[r][4 * k + 3];
            }
        }
#pragma unroll
        for (int r = 0; r < ROWS; ++r) {
            float s = l2 - 2.f * dot[r];
            if (s < best[r]) { best[r] = s; bidx[r] = l; }
        }
    }

#pragma unroll
    for (int r = 0; r < ROWS; ++r) {
        float s = best[r]; int i = bidx[r];
        for (int off = 32; off > 0; off >>= 1) {
            float s2 = __shfl_down(s, off);
            int   i2 = __shfl_down(i, off);
            if (s2 < s || (s2 == s && i2 < i)) { s = s2; i = i2; }
        }
        best[r] = s; bidx[r] = i;
    }

    __shared__ float sbest[4][ROWS];
    __shared__ int   sidx[4][ROWS];
    const int wave = tid >> 6;
    const int lane = tid & 63;
    if (lane == 0) {
#pragma unroll
        for (int r = 0; r < ROWS; ++r) { sbest[wave][r] = best[r]; sidx[wave][r] = bidx[r]; }
    }
    __syncthreads();
    if (tid < ROWS) {
        float s = sbest[0][tid]; int i = sidx[0][tid];
#pragma unroll
        for (int w = 1; w < 4; ++w) {
            float s2 = sbest[w][tid]; int i2 = sidx[w][tid];
            if (s2 < s || (s2 == s && i2 < i)) { s = s2; i = i2; }
        }
        min_idx[b0 + tid] = i;
    }
}

// ---------------- Kernel 2: delta0 write (exact R3 best variant) -----------
__global__ __launch_bounds__(256) void som_delta_kernel(
    const float* __restrict__ x, const float* __restrict__ lm,
    const float* __restrict__ qd, const int* __restrict__ min_idx,
    float* __restrict__ out)
{
    const int l0 = blockIdx.x * CL;
    const int b0 = blockIdx.y * CB;
    const int tid = threadIdx.x;
    const int f4 = tid & 15;
    const int lg = tid >> 4;

    __shared__ float xs[CB][F_DIM];
    __shared__ float hs[CB][CL];
    __shared__ int   bmu[CB];

    {
        const f32x4* src = reinterpret_cast<const f32x4*>(x + (size_t)b0 * F_DIM);
        f32x4* dst = reinterpret_cast<f32x4*>(&xs[0][0]);
        for (int i = tid; i < CB * F_DIM / 4; i += 256) dst[i] = src[i];
    }
    if (tid < CB) bmu[tid] = min_idx[b0 + tid];

    const f32x4 lv = reinterpret_cast<const f32x4*>(lm + (size_t)(l0 + lg) * F_DIM)[f4];

    __syncthreads();

    for (int i = tid; i < CB * CL; i += 256) {
        const int b = i >> 4, j = i & 15;
        hs[b][j] = qd[(size_t)bmu[b] * L_LM + l0 + j];
    }
    __syncthreads();

    float* ob = out + (size_t)b0 * (L_LM * F_DIM) + (size_t)l0 * F_DIM;
#pragma unroll 4
    for (int b = 0; b < CB; ++b) {
        const float h = hs[b][lg];
        const f32x4 xv = reinterpret_cast<const f32x4*>(&xs[b][0])[f4];
        f32x4 o;
        o.x = h * (xv.x - lv.x);
        o.y = h * (xv.y - lv.y);
        o.z = h * (xv.z - lv.z);
        o.w = h * (xv.w - lv.w);
        __builtin_nontemporal_store(
            o, reinterpret_cast<f32x4*>(ob + (size_t)b * (L_LM * F_DIM)) + tid);
    }
}

// ---------------- Diagnostic probes: pure-write fill clones into d_ws ------
// Probe A: constant data (exact rocclr-fill analog). Probe B: full-entropy
// computed data, zero loads. Both: 512 MB, 256 blocks x 256 thr (~fill's
// ~1 block/CU occupancy), grid-stride dwordx4, plain stores, no waits.
// Readout = total dur delta vs R3's 261 us (see round analysis).
typedef unsigned int u32x4 __attribute__((ext_vector_type(4)));

__global__ __launch_bounds__(256) void junk_const_kernel(u32x4* __restrict__ p, unsigned n16)
{
    const unsigned stride = gridDim.x * 256u;
    u32x4 v; v.x = 0xAAAAAAAAu; v.y = 0xAAAAAAAAu; v.z = 0xAAAAAAAAu; v.w = 0xAAAAAAAAu;
    for (unsigned i = blockIdx.x * 256u + threadIdx.x; i < n16; i += stride)
        p[i] = v;
}

__global__ __launch_bounds__(256) void junk_comp_kernel(u32x4* __restrict__ p, unsigned n16)
{
    const unsigned stride = gridDim.x * 256u;
    for (unsigned i = blockIdx.x * 256u + threadIdx.x; i < n16; i += stride) {
        u32x4 v;
        v.x = i * 2654435761u;
        v.y = i * 2246822519u + 0x9E3779B9u;
        v.z = i * 3266489917u + 0x85EBCA6Bu;
        v.w = i * 668265263u  + 0xC2B2AE35u;
        p[i] = v;
    }
}

extern "C" void kernel_launch(void* const* d_in, const int* in_sizes, int n_in,
                              void* d_out, int out_size, void* d_ws, size_t ws_size,
                              hipStream_t stream) {
    const float* x  = (const float*)d_in[0];
    const float* lm = (const float*)d_in[1];
    const float* qd = (const float*)d_in[2];
    float* out = (float*)d_out;
    int* midx = (int*)d_ws;

    som_bmu_kernel<<<B_SZ / 8, 256, 0, stream>>>(x, lm, midx);

    dim3 grid(L_LM / CL, B_SZ / CB);   // (125, 16) = 2000 blocks
    som_delta_kernel<<<grid, 256, 0, stream>>>(x, lm, qd, midx, out);

    // Diagnostic probes (guarded; writes only to scratch, after the real op)
    const size_t PROBE_OFF = (size_t)64 << 20;
    const size_t PROBE_SZ  = (size_t)512 << 20;
    if (ws_size >= PROBE_OFF + 2 * PROBE_SZ) {
        junk_const_kernel<<<256, 256, 0, stream>>>(
            (u32x4*)((char*)d_ws + PROBE_OFF), 1u << 25);
        junk_comp_kernel<<<256, 256, 0, stream>>>(
            (u32x4*)((char*)d_ws + PROBE_OFF + PROBE_SZ), 1u << 25);
    }
}